// Round 1
// baseline (521.195 us; speedup 1.0000x reference)
//
#include <hip/hip_runtime.h>

#define B_    2
#define S_    1024
#define H_    4096
#define NH_   32
#define DH_   128
#define NKV_  2
#define GROUP_ 16
#define ROT_  64
#define NQKV_ 4608   // NH*DH + 2*NKV*DH
#define SCALE_ 0.08838834764831845f  // 128^-0.5

typedef __attribute__((ext_vector_type(8))) short bf16x8;
typedef __attribute__((ext_vector_type(4))) float f32x4;

typedef __attribute__((address_space(1))) const void* gptr_t;
typedef __attribute__((address_space(3))) void* lptr_t;

__device__ __forceinline__ unsigned short f2bf(float f) {
    unsigned int u = __builtin_bit_cast(unsigned int, f);
    u += 0x7FFFu + ((u >> 16) & 1u);   // RNE
    return (unsigned short)(u >> 16);
}

// ---------------- convert fp32 -> bf16 (vectorized) ----------------
__global__ void k_f32_to_bf16(const float* __restrict__ in,
                              unsigned short* __restrict__ out, int n4) {
    int i = blockIdx.x * blockDim.x + threadIdx.x;
    if (i >= n4) return;
    const float4 v = reinterpret_cast<const float4*>(in)[i];
    ushort4 o;
    o.x = f2bf(v.x); o.y = f2bf(v.y); o.z = f2bf(v.z); o.w = f2bf(v.w);
    reinterpret_cast<ushort4*>(out)[i] = o;
}

// ------------- transpose fp32 [K][N] -> bf16 [N][K] ----------------
__global__ void k_transpose_bf16(const float* __restrict__ in,
                                 unsigned short* __restrict__ out,
                                 int K, int N) {
    __shared__ float tile[32][33];
    const int n0 = blockIdx.x * 32, k0 = blockIdx.y * 32;
    const int tx = threadIdx.x, ty = threadIdx.y;
    for (int j = ty; j < 32; j += 8)
        tile[j][tx] = in[(size_t)(k0 + j) * N + n0 + tx];
    __syncthreads();
    for (int j = ty; j < 32; j += 8)
        out[(size_t)(n0 + j) * K + k0 + tx] = f2bf(tile[tx][j]);
}

// ------------- bf16 GEMM, m97 structure: C = A * Bt^T (+bias) -------------
// A [M][K] bf16, Bt [N][K] bf16, C fp32 and/or bf16. 128x128 tile, BK=32.
__global__ __launch_bounds__(256) void k_gemm_bt(
    const unsigned short* __restrict__ A,
    const unsigned short* __restrict__ Bt,
    const float* __restrict__ bias,
    float* __restrict__ Cf,
    unsigned short* __restrict__ Cbf,
    int M, int N, int K)
{
    __shared__ unsigned short lds_a[128 * 32];
    __shared__ unsigned short lds_b[128 * 32];
    const int tid  = threadIdx.x;
    const int wave = tid >> 6, lane = tid & 63;
    const int lrow = lane & 15, lhi = lane >> 4;
    const int wm = (wave >> 1) * 64, wn = (wave & 1) * 64;
    const size_t a_row0 = (size_t)blockIdx.y * 128;
    const size_t b_row0 = (size_t)blockIdx.x * 128;

    f32x4 acc[4][4] = {};

    // staging map: segment seg covers LDS bytes [seg*1024, +1024), lane l -> +l*16
    const int seg0 = wave * 2;
    const int idx0 = seg0 * 512 + lane * 8;        // element index in [128][32]
    const int r0 = idx0 >> 5, kk0 = idx0 & 31;
    const int idx1 = (seg0 + 1) * 512 + lane * 8;
    const int r1 = idx1 >> 5, kk1 = idx1 & 31;

    for (int k0 = 0; k0 < K; k0 += 32) {
        __syncthreads();   // previous iter's reads done before overwrite
        __builtin_amdgcn_global_load_lds(
            (gptr_t)(const void*)(A + (a_row0 + r0) * K + k0 + kk0),
            (lptr_t)(void*)((char*)lds_a + seg0 * 1024), 16, 0, 0);
        __builtin_amdgcn_global_load_lds(
            (gptr_t)(const void*)(A + (a_row0 + r1) * K + k0 + kk1),
            (lptr_t)(void*)((char*)lds_a + (seg0 + 1) * 1024), 16, 0, 0);
        __builtin_amdgcn_global_load_lds(
            (gptr_t)(const void*)(Bt + (b_row0 + r0) * K + k0 + kk0),
            (lptr_t)(void*)((char*)lds_b + seg0 * 1024), 16, 0, 0);
        __builtin_amdgcn_global_load_lds(
            (gptr_t)(const void*)(Bt + (b_row0 + r1) * K + k0 + kk1),
            (lptr_t)(void*)((char*)lds_b + (seg0 + 1) * 1024), 16, 0, 0);
        __syncthreads();   // compiler drains vmcnt before s_barrier

        bf16x8 af[4], bfr[4];
        #pragma unroll
        for (int i = 0; i < 4; i++)
            af[i] = *(const bf16x8*)(&lds_a[(wm + i * 16 + lrow) * 32 + lhi * 8]);
        #pragma unroll
        for (int j = 0; j < 4; j++)
            bfr[j] = *(const bf16x8*)(&lds_b[(wn + j * 16 + lrow) * 32 + lhi * 8]);
        #pragma unroll
        for (int i = 0; i < 4; i++)
            #pragma unroll
            for (int j = 0; j < 4; j++)
                acc[i][j] = __builtin_amdgcn_mfma_f32_16x16x32_bf16(
                    af[i], bfr[j], acc[i][j], 0, 0, 0);
    }

    // epilogue: C/D layout col=lane&15, row=(lane>>4)*4+r
    #pragma unroll
    for (int i = 0; i < 4; i++)
        #pragma unroll
        for (int j = 0; j < 4; j++) {
            const size_t grow0 = a_row0 + wm + i * 16 + lhi * 4;
            const size_t gcol  = b_row0 + wn + j * 16 + lrow;
            const float bi = bias ? bias[gcol] : 0.f;
            #pragma unroll
            for (int r = 0; r < 4; r++) {
                const float v = acc[i][j][r] + bi;
                if (Cf)  Cf[(grow0 + r) * N + gcol] = v;
                if (Cbf) Cbf[(grow0 + r) * N + gcol] = f2bf(v);
            }
        }
}

// ------------- RoPE (GLM interleaved, first 64 dims) + reorg -------------
// qkv fp32 [B*S][4608] -> Qh bf16 [B][NH][S][DH], Kh bf16 [B][NKV][S][DH],
//                         Vt bf16 [B][NKV][DH][S]
__global__ void k_rope_reorg(const float* __restrict__ qkv,
                             const int* __restrict__ pos_ids,
                             unsigned short* __restrict__ Qh,
                             unsigned short* __restrict__ Kh,
                             unsigned short* __restrict__ Vt)
{
    const int NPR = (NH_ + 2 * NKV_) * 64;   // 2304 work units per token row
    const int idx = blockIdx.x * blockDim.x + threadIdx.x;
    if (idx >= B_ * S_ * NPR) return;
    const int t = idx / NPR;
    const int rem = idx % NPR;
    const int unit = rem >> 6;
    const int pr = rem & 63;        // pair index: elems 2*pr, 2*pr+1
    const int b = t >> 10, s = t & 1023;
    const float pos = (float)pos_ids[t];
    const float* row = qkv + (size_t)t * NQKV_;

    if (unit < NH_) {               // Q head
        const int col = unit * DH_ + 2 * pr;
        float x0 = row[col], x1 = row[col + 1];
        if (pr < 32) {
            const float ang = pos * powf(10000.f, -(float)pr / 32.f);
            float sn, cs; sincosf(ang, &sn, &cs);
            const float o0 = x0 * cs - x1 * sn;
            const float o1 = x1 * cs + x0 * sn;
            x0 = o0; x1 = o1;
        }
        unsigned short* dst = Qh + ((size_t)((b * NH_ + unit) * S_) + s) * DH_ + 2 * pr;
        dst[0] = f2bf(x0); dst[1] = f2bf(x1);
    } else if (unit < NH_ + NKV_) { // K head
        const int g = unit - NH_;
        const int col = NH_ * DH_ + g * DH_ + 2 * pr;
        float x0 = row[col], x1 = row[col + 1];
        if (pr < 32) {
            const float ang = pos * powf(10000.f, -(float)pr / 32.f);
            float sn, cs; sincosf(ang, &sn, &cs);
            const float o0 = x0 * cs - x1 * sn;
            const float o1 = x1 * cs + x0 * sn;
            x0 = o0; x1 = o1;
        }
        unsigned short* dst = Kh + ((size_t)((b * NKV_ + g) * S_) + s) * DH_ + 2 * pr;
        dst[0] = f2bf(x0); dst[1] = f2bf(x1);
    } else {                        // V head -> transposed [DH][S]
        const int g = unit - NH_ - NKV_;
        const int col = NH_ * DH_ + NKV_ * DH_ + g * DH_ + 2 * pr;
        const float x0 = row[col], x1 = row[col + 1];
        unsigned short* d0 = Vt + ((size_t)((b * NKV_ + g) * DH_) + 2 * pr) * S_ + s;
        d0[0]  = f2bf(x0);
        d0[S_] = f2bf(x1);
    }
}

// ------------- flash attention: 1 wave/block, 16 q-rows, kv tiles of 32 -----
__global__ __launch_bounds__(64) void k_attn(
    const unsigned short* __restrict__ Qh,
    const unsigned short* __restrict__ Kh,
    const unsigned short* __restrict__ Vt,
    unsigned short* __restrict__ ctx)   // [B][S][NH*DH] bf16
{
    __shared__ unsigned short lds_p[16 * 32];
    const int lane = threadIdx.x;
    const int lrow = lane & 15, lhi = lane >> 4;
    const int blk = blockIdx.x;
    const int qt = blk & 63;            // S/16 = 64 q-tiles
    const int h  = (blk >> 6) & 31;
    const int b  = blk >> 11;
    const int g  = h >> 4;              // kv head = h / GROUP
    const int q0 = qt * 16;

    const unsigned short* Qbase = Qh + ((size_t)((b * NH_ + h) * S_) + q0) * DH_;
    const unsigned short* Kbase = Kh + (size_t)((b * NKV_ + g) * S_) * DH_;
    const unsigned short* Vbase = Vt + (size_t)((b * NKV_ + g) * DH_) * S_;

    // Q A-fragments: lane holds row (lane&15), k = (lane>>4)*8.. (+8), 4 k-slices
    bf16x8 a_q[4];
    #pragma unroll
    for (int ks = 0; ks < 4; ks++)
        a_q[ks] = *(const bf16x8*)(Qbase + (size_t)lrow * DH_ + ks * 32 + lhi * 8);

    float m_run[4], l_run[4];
    #pragma unroll
    for (int r = 0; r < 4; r++) { m_run[r] = -1e30f; l_run[r] = 0.f; }
    f32x4 o_acc[8] = {};

    const int ntiles = (q0 + 16 + 31) >> 5;   // causal: kv < q0+16
    for (int t = 0; t < ntiles; t++) {
        const int kv0 = t * 32;
        // ---- QK^T: scores [16 q][32 kv], two 16-col mfma tiles ----
        f32x4 s_acc[2] = {};
        #pragma unroll
        for (int nt = 0; nt < 2; nt++)
            #pragma unroll
            for (int ks = 0; ks < 4; ks++) {
                const bf16x8 b_k = *(const bf16x8*)(
                    Kbase + (size_t)(kv0 + nt * 16 + lrow) * DH_ + ks * 32 + lhi * 8);
                s_acc[nt] = __builtin_amdgcn_mfma_f32_16x16x32_bf16(
                    a_q[ks], b_k, s_acc[nt], 0, 0, 0);
            }
        // ---- mask + scale + row max (reduce across 16-lane group) ----
        float p[2][4], pmax[4];
        #pragma unroll
        for (int r = 0; r < 4; r++) {
            const int qrow = q0 + lhi * 4 + r;
            float mx = -1e30f;
            #pragma unroll
            for (int nt = 0; nt < 2; nt++) {
                float sv = s_acc[nt][r] * SCALE_;
                if (kv0 + nt * 16 + lrow > qrow) sv = -1e30f;
                p[nt][r] = sv;
                mx = fmaxf(mx, sv);
            }
            #pragma unroll
            for (int off = 1; off < 16; off <<= 1)
                mx = fmaxf(mx, __shfl_xor(mx, off));
            pmax[r] = mx;
        }
        // ---- online softmax update ----
        float scale_r[4], sum_r[4];
        #pragma unroll
        for (int r = 0; r < 4; r++) {
            const float mnew = fmaxf(m_run[r], pmax[r]);
            scale_r[r] = __expf(m_run[r] - mnew);
            m_run[r] = mnew;
            sum_r[r] = 0.f;
        }
        #pragma unroll
        for (int nt = 0; nt < 2; nt++)
            #pragma unroll
            for (int r = 0; r < 4; r++) {
                const float e = __expf(p[nt][r] - m_run[r]);  // masked -> 0
                p[nt][r] = e;
                sum_r[r] += e;
            }
        #pragma unroll
        for (int r = 0; r < 4; r++) {
            float sm = sum_r[r];
            #pragma unroll
            for (int off = 1; off < 16; off <<= 1)
                sm += __shfl_xor(sm, off);
            l_run[r] = l_run[r] * scale_r[r] + sm;
        }
        #pragma unroll
        for (int d = 0; d < 8; d++)
            #pragma unroll
            for (int r = 0; r < 4; r++)
                o_acc[d][r] *= scale_r[r];
        // ---- P -> LDS (transpose to A-fragment layout), bf16 ----
        #pragma unroll
        for (int nt = 0; nt < 2; nt++)
            #pragma unroll
            for (int r = 0; r < 4; r++)
                lds_p[(lhi * 4 + r) * 32 + nt * 16 + lrow] = f2bf(p[nt][r]);
        __syncthreads();
        const bf16x8 a_p = *(const bf16x8*)(&lds_p[lrow * 32 + lhi * 8]);
        // ---- PV: ctx[16 q][128 dh] += P[16][32] * V[32][128] ----
        #pragma unroll
        for (int d = 0; d < 8; d++) {
            const bf16x8 b_v = *(const bf16x8*)(
                Vbase + (size_t)(d * 16 + lrow) * S_ + kv0 + lhi * 8);
            o_acc[d] = __builtin_amdgcn_mfma_f32_16x16x32_bf16(
                a_p, b_v, o_acc[d], 0, 0, 0);
        }
        __syncthreads();
    }
    // ---- finalize: divide by l, store bf16 ctx ----
    float inv_l[4];
    #pragma unroll
    for (int r = 0; r < 4; r++) inv_l[r] = 1.f / l_run[r];
    #pragma unroll
    for (int d = 0; d < 8; d++)
        #pragma unroll
        for (int r = 0; r < 4; r++) {
            const size_t row = (size_t)b * S_ + q0 + lhi * 4 + r;
            ctx[row * (NH_ * DH_) + h * DH_ + d * 16 + lrow] =
                f2bf(o_acc[d][r] * inv_l[r]);
        }
}

// --------------------------------------------------------------------------
extern "C" void kernel_launch(void* const* d_in, const int* in_sizes, int n_in,
                              void* d_out, int out_size, void* d_ws, size_t ws_size,
                              hipStream_t stream)
{
    const float* hidden  = (const float*)d_in[0];
    const int*   pos_ids = (const int*)d_in[1];
    const float* W_qkv   = (const float*)d_in[2];
    const float* b_qkv   = (const float*)d_in[3];
    const float* W_dense = (const float*)d_in[4];
    float* out = (float*)d_out;

    char* ws = (char*)d_ws;
    unsigned short* Xbf = (unsigned short*)(ws);                  // 16 MB
    unsigned short* Wqt = (unsigned short*)(ws + 16777216);       // 36 MB [4608][4096]
    unsigned short* Wdt = (unsigned short*)(ws + 54525952);       // 32 MB [4096][4096]
    float*          qkv = (float*)         (ws + 88080384);       // 36 MB [2048][4608]
    unsigned short* Qh  = (unsigned short*)(ws + 125829120);      // 16 MB
    unsigned short* Kh  = (unsigned short*)(ws + 142606336);      //  1 MB
    unsigned short* Vt  = (unsigned short*)(ws + 143654912);      //  1 MB
    unsigned short* Ctx = (unsigned short*)(ws + 144703488);      // 16 MB

    const int M = B_ * S_;   // 2048

    // 1. hidden -> bf16
    k_f32_to_bf16<<<(M * H_ / 4 + 255) / 256, 256, 0, stream>>>(hidden, Xbf, M * H_ / 4);
    // 2. weight transposes (fp32 [K][N] -> bf16 [N][K])
    dim3 tb(32, 8);
    k_transpose_bf16<<<dim3(NQKV_ / 32, H_ / 32), tb, 0, stream>>>(W_qkv, Wqt, H_, NQKV_);
    k_transpose_bf16<<<dim3(H_ / 32, H_ / 32), tb, 0, stream>>>(W_dense, Wdt, H_, H_);
    // 3. QKV projection: qkv = X @ W_qkv + b
    k_gemm_bt<<<dim3(NQKV_ / 128, M / 128), 256, 0, stream>>>(
        Xbf, Wqt, b_qkv, qkv, nullptr, M, NQKV_, H_);
    // 4. RoPE + head reorg + V transpose
    k_rope_reorg<<<(M * 2304 + 255) / 256, 256, 0, stream>>>(qkv, pos_ids, Qh, Kh, Vt);
    // 5. causal GQA attention -> ctx bf16
    k_attn<<<B_ * NH_ * (S_ / 16), 64, 0, stream>>>(Qh, Kh, Vt, Ctx);
    // 6. dense projection: out = ctx @ W_dense
    k_gemm_bt<<<dim3(H_ / 128, M / 128), 256, 0, stream>>>(
        Ctx, Wdt, nullptr, out, nullptr, M, H_, H_);
}